// Round 1
// baseline (71.261 us; speedup 1.0000x reference)
//
#include <hip/hip_runtime.h>

#define BATCH 1024
#define NCOLS 8192
#define NROWS 8192
#define NNZPR 32

// ---------------------------------------------------------------------------
// Kernel 1: transpose X (BATCH x NCOLS) -> XT (NCOLS x BATCH), 64x64 LDS tiles
// ---------------------------------------------------------------------------
__global__ __launch_bounds__(256) void transpose_x(const float* __restrict__ x,
                                                   float* __restrict__ xt) {
    __shared__ float tile[64][65];          // +1 pad: conflict-free both phases
    const int c0 = blockIdx.x * 64;         // column tile of X (0..127)
    const int b0 = blockIdx.y * 64;         // batch tile of X (0..15)
    const int tx = threadIdx.x & 63;
    const int ty = threadIdx.x >> 6;        // 0..3

#pragma unroll
    for (int i = 0; i < 16; ++i) {
        const int b = ty + i * 4;
        // coalesced read: lanes sweep contiguous columns
        tile[b][tx] = x[(size_t)(b0 + b) * NCOLS + c0 + tx];
    }
    __syncthreads();
#pragma unroll
    for (int i = 0; i < 16; ++i) {
        const int c = ty + i * 4;
        // coalesced write: lanes sweep contiguous batches
        xt[(size_t)(c0 + c) * BATCH + b0 + tx] = tile[tx][c];
    }
}

// ---------------------------------------------------------------------------
// Kernel 2: out[b][r] = sum_k xsrc[col, b] * val  for 64-row x 64-batch tiles.
// Address of element (c, b) = xsrc[c*cstride + b*bstride]:
//   transposed path: cstride=BATCH, bstride=1  (coalesced over lanes=batch)
//   fallback path:   cstride=1, bstride=NCOLS  (slow, correctness insurance)
// ---------------------------------------------------------------------------
__global__ __launch_bounds__(256) void spmm_tile(const float* __restrict__ xsrc,
                                                 const float* __restrict__ vals,
                                                 const int*   __restrict__ cols,
                                                 float* __restrict__ out,
                                                 int cstride, int bstride) {
    // LDS: phase 1 holds 2048 (col,val) pairs (16 KiB); phase 2 reuses it as
    // a padded 64x65 f32 transpose tile (16640 B).
    __shared__ __align__(16) char smem_raw[64 * 65 * 4];
    int*   s_col = (int*)smem_raw;                   // [64*32]
    float* s_val = (float*)(smem_raw + 64 * 32 * 4); // [64*32]

    const int bid  = blockIdx.x;
    const int bt   = bid & 15;       // batch tile (0..15) -> XCD = bt & 7
    const int rt   = bid >> 4;       // row tile (0..127)
    const int t    = threadIdx.x;
    const int lane = t & 63;
    const int wave = t >> 6;         // 0..3

    // stage this row-tile's nnz metadata (rows are repeat(arange), so row r's
    // entries live at [r*32, r*32+32))
    const int nnzbase = rt * 64 * NNZPR;
    for (int i = t; i < 64 * NNZPR; i += 256) {
        s_col[i] = cols[nnzbase + i];
        s_val[i] = vals[nnzbase + i];
    }
    __syncthreads();

    const int b = bt * 64 + lane;
    const float* __restrict__ xb = xsrc + (size_t)b * bstride;

    float acc[16];
#pragma unroll
    for (int i = 0; i < 16; ++i) acc[i] = 0.f;

    const int rbase = wave * 16;     // each wave owns 16 rows of the tile
    for (int i = 0; i < 16; ++i) {
        const int p = (rbase + i) * NNZPR;
        float a = 0.f;
#pragma unroll
        for (int k = 0; k < NNZPR; ++k) {
            const int   c = s_col[p + k];   // wave-uniform broadcast
            const float v = s_val[p + k];
            a += xb[c * cstride] * v;       // coalesced 256B wave-load (path A)
        }
        acc[i] = a;
    }
    __syncthreads();   // all reads of s_col/s_val done; reuse LDS

    // transpose result tile through LDS for coalesced output stores
    float* tile = (float*)smem_raw;  // [64][65]
#pragma unroll
    for (int i = 0; i < 16; ++i)
        tile[lane * 65 + rbase + i] = acc[i];   // stride 65 -> conflict-free
    __syncthreads();

    const int rl  = t & 63;
    const int bl0 = t >> 6;
    const size_t obase = (size_t)(bt * 64) * NROWS + (size_t)rt * 64;
#pragma unroll
    for (int p = 0; p < 16; ++p) {
        const int bl = bl0 + p * 4;
        // lanes sweep contiguous r: 256B contiguous store per wave
        out[obase + (size_t)bl * NROWS + rl] = tile[bl * 65 + rl];
    }
}

extern "C" void kernel_launch(void* const* d_in, const int* in_sizes, int n_in,
                              void* d_out, int out_size, void* d_ws, size_t ws_size,
                              hipStream_t stream) {
    const float* x    = (const float*)d_in[0];   // (BATCH, NCOLS) f32
    const float* vals = (const float*)d_in[1];   // (NNZ,) f32
    // d_in[2] = rows: repeat(arange(NROWS), 32) -- structure known, unused
    const int*   cols = (const int*)d_in[3];     // (NNZ,) i32
    float* out = (float*)d_out;                  // (BATCH, NROWS) f32

    const size_t xt_bytes = (size_t)NCOLS * BATCH * sizeof(float);
    if (ws_size >= xt_bytes) {
        float* xt = (float*)d_ws;
        dim3 tgrid(NCOLS / 64, BATCH / 64);
        transpose_x<<<tgrid, 256, 0, stream>>>(x, xt);
        spmm_tile<<<(NROWS / 64) * (BATCH / 64), 256, 0, stream>>>(
            xt, vals, cols, out, BATCH, 1);
    } else {
        spmm_tile<<<(NROWS / 64) * (BATCH / 64), 256, 0, stream>>>(
            x, vals, cols, out, 1, NCOLS);
    }
}